// Round 10
// baseline (185.602 us; speedup 1.0000x reference)
//
#include <hip/hip_runtime.h>
#include <math.h>

// Problem constants
#define BATCH 2
#define SEQ   2048
#define NH    16
#define HD    64
#define DM    1024
#define MROWS (BATCH * SEQ)                  // 4096
#define NEL   ((size_t)MROWS * DM)           // 4 M elements (activation buffer)
#define WEL   ((size_t)DM * DM)              // 1 M elements (weight buffer)
// softmax scale folded into Q at projection: 1/sqrt(64) * log2(e)
#define SM_SCALE_LOG2E 0.18033688011112042f

typedef __bf16 bf16x8 __attribute__((ext_vector_type(8)));
typedef float  f32x4  __attribute__((ext_vector_type(4)));

#define MFMA16(a, b, c) __builtin_amdgcn_mfma_f32_16x16x32_bf16((a), (b), (c), 0, 0, 0)
#define EXP2(x) __builtin_amdgcn_exp2f(x)

// async global->LDS, 16B per lane; LDS dest = wave-uniform base + lane*16
#define GLDS16(g, s) __builtin_amdgcn_global_load_lds( \
    (const __attribute__((address_space(1))) void*)(g), \
    (__attribute__((address_space(3))) void*)(s), 16, 0, 0)

// ----------------------------------------------------------------------
// Verified levers: K/V/Q k-chunk swizzle (R2), Pt chunk^row swizzle (R3),
// XCD pinning attn (R3) + GEMMs (R7), KVBLK=128+deferred l_i (R5),
// Vt LDS-transpose (R6).
// Schedule lessons (R4/R8/R9 all regressed): keep 2 independent blocks
// per CU; KVBLK=128 + plain __syncthreads is this loop's optimum;
// counted-vmcnt needs a full 8-phase structure (regime gate) - null here.
// R10: T15 double-pipeline inside the tile: QK of BOTH 64-key sub-phases
// issued up front (st[2][..]), then SM0/PV0, SM1/PV1. SM0's wait on QK0
// results hides under QK1 issue; PV0 execution covers SM1. Pure reorder.
// ----------------------------------------------------------------------

// ======================================================================
// fp32 -> bf16 convert, single launch: blocks [0,4096) convert x,
// blocks [4096,8192) convert the 4 weight matrices.
// ======================================================================
__global__ __launch_bounds__(256) void cvt_all(
    const float* __restrict__ x,
    const float* __restrict__ w0, const float* __restrict__ w1,
    const float* __restrict__ w2, const float* __restrict__ w3,
    __bf16* __restrict__ xb, __bf16* __restrict__ wb)
{
    const int bid = blockIdx.x;
    const float* src;
    __bf16* dst;
    size_t base;
    if (bid < 4096) {
        src = x; dst = xb; base = (size_t)bid * 1024;
    } else {
        const int r = bid - 4096;
        const int z = r >> 10;
        src = (z == 0) ? w0 : (z == 1) ? w1 : (z == 2) ? w2 : w3;
        dst = wb + (size_t)z * WEL;
        base = (size_t)(r & 1023) * 1024;
    }
    const size_t i = base + (size_t)threadIdx.x * 4;
    const float4 f = *(const float4*)&src[i];
    __bf16 b[4] = {(__bf16)f.x, (__bf16)f.y, (__bf16)f.z, (__bf16)f.w};
    *(ushort4*)&dst[i] = *(ushort4*)b;
}

// ======================================================================
// NT bf16 MFMA GEMM, single-barrier double-buffered K-loop.
// C[m,n] = sum_k A[m,k]*W[n,k]. Tile 128 x BN, BK=32, 4 waves.
// 1D XCD-pinned grid: id -> (xcd=id&7, x, z, yq), y = xcd*4+yq.
// LDS k-chunk XOR-swizzled -> conflict-free b128 fragment reads.
// NZ=3 (BN=128, mode 1): z selects weight+output slab; bf16 store
//   permuted to (B,H,S,HD); z==0 (Q) pre-scaled; z==2 (V) additionally
//   transposed through LDS and stored coalesced to Vt (B,H,HD,S).
// NZ=1 (mode 0): fp32 row-major M x DM store.
// ======================================================================
template<int BN, int NZ>
__global__ __launch_bounds__(256) void gemm_nt_mfma(
    const __bf16* __restrict__ A, const __bf16* __restrict__ W0,
    void* __restrict__ C0, __bf16* __restrict__ Vt, int mode)
{
    constexpr int NI  = BN / 32;         // 16-col groups per wave
    constexpr int NIT = DM / 32;         // 32 K-iterations
    constexpr int NX  = DM / BN;         // 8 (BN=128) or 16 (BN=64)
    constexpr int LNX = (BN == 128) ? 3 : 4;
    // flat LDS: A dbuf (2x4096) + B dbuf (2x BN*32); for BN=128 the whole
    // 16384-elem pool is reused as the 128x128 transpose buffer T.
    __shared__ __bf16 lds[2 * 128 * 32 + 2 * BN * 32];
    #define AST(buf) (lds + (buf) * 4096)
    #define BST(buf) (lds + 8192 + (buf) * (BN * 32))

    const int t = threadIdx.x;
    const int w = t >> 6, l = t & 63;
    const int quad = l >> 4, l15 = l & 15;

    // XCD-pinned decomposition (bijective: 8 * NX * 4*NZ blocks)
    const int id  = blockIdx.x;
    const int xcd = id & 7;
    const int g   = id >> 3;
    const int x   = g & (NX - 1);
    const int r0  = g >> LNX;            // [0, 4*NZ)
    const int z   = r0 >> 2;
    const int yq  = r0 & 3;
    const int y   = xcd * 4 + yq;
    const int m0 = y * 128, n0 = x * BN;
    const int wm = (w >> 1) * 64, wn = (w & 1) * (BN / 2);

    const __bf16* Wp = W0 + (size_t)z * WEL;

    const int lrow = l >> 2;           // staging: lane row within 16-row instr
    // staging k-offset: pre-swizzled global source column (rule #21)
    const int lkof = ((l & 3) ^ ((lrow >> 1) & 3)) * 8;
    // read-side swizzled k-chunk (row bits 1..2 == l15 bits 1..2)
    const int qsw = (quad ^ ((l15 >> 1) & 3)) * 8;

    const __bf16* Ag = A + (size_t)(m0 + w * 32 + lrow) * DM + lkof;
    const int aoff = (w * 32) * 32;    // wave-uniform LDS offset (A)
    // B staging: BN=128 -> 2 instrs/wave (rows w*32); BN=64 -> 1 (rows w*16)
    const int brow = (BN == 128) ? (w * 32) : (w * 16);
    const __bf16* Bg = Wp + (size_t)(n0 + brow + lrow) * DM + lkof;
    const int boff = brow * 32;

    f32x4 acc[4][NI];
    #pragma unroll
    for (int i = 0; i < 4; i++)
        #pragma unroll
        for (int j = 0; j < NI; j++) acc[i][j] = (f32x4)0.0f;

    // prologue: tile 0 -> buf 0
    GLDS16(Ag,           AST(0) + aoff);
    GLDS16(Ag + 16 * DM, AST(0) + aoff + 512);
    GLDS16(Bg,           BST(0) + boff);
    if (BN == 128) GLDS16(Bg + 16 * DM, BST(0) + boff + 512);
    __syncthreads();

    for (int i = 0; i < NIT; i++) {
        const int cur = i & 1, nxt = cur ^ 1;
        if (i + 1 < NIT) {
            const int k0 = (i + 1) * 32;
            GLDS16(Ag + k0,           AST(nxt) + aoff);
            GLDS16(Ag + k0 + 16 * DM, AST(nxt) + aoff + 512);
            GLDS16(Bg + k0,           BST(nxt) + boff);
            if (BN == 128) GLDS16(Bg + k0 + 16 * DM, BST(nxt) + boff + 512);
        }

        bf16x8 af[4], bfr[NI];
        #pragma unroll
        for (int mi = 0; mi < 4; mi++)
            af[mi] = *(const bf16x8*)&AST(cur)[(wm + mi * 16 + l15) * 32 + qsw];
        #pragma unroll
        for (int ni = 0; ni < NI; ni++)
            bfr[ni] = *(const bf16x8*)&BST(cur)[(wn + ni * 16 + l15) * 32 + qsw];
        __builtin_amdgcn_s_setprio(1);
        #pragma unroll
        for (int mi = 0; mi < 4; mi++)
            #pragma unroll
            for (int ni = 0; ni < NI; ni++)
                acc[mi][ni] = MFMA16(af[mi], bfr[ni], acc[mi][ni]);
        __builtin_amdgcn_s_setprio(0);

        __syncthreads();   // single barrier: drains prefetch, fences buffers
    }

    if (mode) {
        const float sc = (z == 0) ? SM_SCALE_LOG2E : 1.0f;
        __bf16* C = (__bf16*)C0 + (size_t)z * NEL;
        #pragma unroll
        for (int mi = 0; mi < 4; mi++)
            #pragma unroll
            for (int ni = 0; ni < NI; ni++)
                #pragma unroll
                for (int r = 0; r < 4; r++) {
                    const int row = m0 + wm + mi * 16 + quad * 4 + r;
                    const int col = n0 + wn + ni * 16 + l15;
                    const int b = row >> 11, s = row & (SEQ - 1);
                    const int h = col >> 6,  d = col & (HD - 1);
                    const __bf16 val = (__bf16)(acc[mi][ni][r] * sc);
                    C[((size_t)(b * NH + h) * SEQ + s) * HD + d] = val;
                }

        if constexpr (BN == 128) {
            if (z == 2) {
                // ---- Vt via LDS transpose: T[col 128][s 128], 16B-chunk
                // swizzle sc^(col&7). acc r-values are s-consecutive ->
                // one 8B packed write per (mi,ni).
                __bf16* T = lds;   // staging buffers dead after final barrier
                #pragma unroll
                for (int mi = 0; mi < 4; mi++)
                    #pragma unroll
                    for (int ni = 0; ni < 4; ni++) {
                        const int cl = wn + ni * 16 + l15;
                        const int s0 = wm + mi * 16 + quad * 4;
                        __bf16 pb[4] = {(__bf16)acc[mi][ni][0], (__bf16)acc[mi][ni][1],
                                        (__bf16)acc[mi][ni][2], (__bf16)acc[mi][ni][3]};
                        const int scn = s0 >> 3;          // 16B chunk along s
                        const int sub = (s0 >> 2) & 1;    // 8B half
                        *(uint2*)&T[cl * 128 + ((scn ^ (cl & 7)) * 8) + sub * 4] =
                            *(uint2*)pb;
                    }
                __syncthreads();
                // read back coalesced: per instr, 8 cols x 8 consecutive
                // 16B chunks (128B runs) -> uint4 stores to Vt
                const int b = m0 >> 11;
                const int sbase = m0 & (SEQ - 1);
                #pragma unroll
                for (int u = 0; u < 8; u++) {
                    const int cl = ((u >> 1) * 32) + (t >> 3);
                    const int ci = (u & 1) * 8 + (t & 7);
                    const int hh = (n0 + cl) >> 6, dd = (n0 + cl) & (HD - 1);
                    const uint4 v = *(const uint4*)&T[cl * 128 + ((ci ^ (cl & 7)) * 8)];
                    *(uint4*)&Vt[((size_t)(b * NH + hh) * HD + dd) * SEQ +
                                 sbase + ci * 8] = v;
                }
            }
        }
    } else {
        float* C = (float*)C0;
        #pragma unroll
        for (int mi = 0; mi < 4; mi++)
            #pragma unroll
            for (int ni = 0; ni < NI; ni++)
                #pragma unroll
                for (int r = 0; r < 4; r++) {
                    const int row = m0 + wm + mi * 16 + quad * 4 + r;
                    const int col = n0 + wn + ni * 16 + l15;
                    C[(size_t)row * DM + col] = acc[mi][ni][r];
                }
    }
    #undef AST
    #undef BST
}

// ======================================================================
// Flash attention v11: R7's v8 (4-wave/128q, KVBLK=128, dbuf,
// __syncthreads) + T15 double-pipeline: QK of BOTH 64-key sub-phases
// issued before softmax/PV of either. st doubled (static indices via
// full unroll). Everything else unchanged: deferred l_i, swizzled
// K/V/Q + Pt, setprio, XCD-pinned 1D grid.
// LDS: KV dbuf 2 x 32 KB + Pt 16 KB = 80 KB -> 2 blocks/CU (grid 512).
// ======================================================================
__global__ __launch_bounds__(256, 2) void attn_mfma(
    const __bf16* __restrict__ Q, const __bf16* __restrict__ K,
    const __bf16* __restrict__ Vt, const __bf16* __restrict__ V,
    const float* __restrict__ xsa, __bf16* __restrict__ X2)
{
    // KV[buf][0] = K region [h][key128][32]  (h*4096 + key*32 + j)
    // KV[buf][1] = V region [kg][dim64][32]  (kg*2048 + dim*32 + j), kg=key/32
    __shared__ __bf16 KV[2][2][8192];
    __shared__ __bf16 Pt[4][32][64];   // per-wave P [q][key64], XOR-swizzled

    const int t = threadIdx.x;
    const int w = t >> 6, l = t & 63;
    const int quad = l >> 4, l15 = l & 15;
    // XCD-pinned decomposition: id%8 == bh%8 -> one XCD per (b,h)
    const int bh = blockIdx.x & 31;
    const int q0 = (blockIdx.x >> 5) * 128;

    const __bf16* Qb  = Q  + (size_t)bh * SEQ * HD;
    const __bf16* Kb  = K  + (size_t)bh * SEQ * HD;
    const __bf16* Vtb = Vt + (size_t)bh * HD * SEQ;

    const int lrow = l >> 2;
    // staging k-offset: pre-swizzled global source column (rule #21)
    const int lkof = ((l & 3) ^ ((lrow >> 1) & 3)) * 8;
    // read-side swizzled k-chunk
    const int qsw = (quad ^ ((l15 >> 1) & 3)) * 8;
    // Pt swizzle key: row & 7 == l15 & 7 for all Pt accesses
    const int pkey = l15 & 7;

    // ---- prologue: stage Q into KV[1][0] (16 KB overlay) + K0/V0 -> KV[0]
    __bf16* Qst = &KV[1][0][0];   // flat [h][q128][32]: h*4096 + q*32 + j
    #pragma unroll
    for (int h = 0; h < 2; h++)
        #pragma unroll
        for (int qq = 0; qq < 2; qq++)
            GLDS16(Qb + (size_t)(q0 + w * 32 + qq * 16 + lrow) * HD + h * 32 + lkof,
                   Qst + h * 4096 + (w * 32 + qq * 16) * 32);
    #pragma unroll
    for (int h = 0; h < 2; h++)
        #pragma unroll
        for (int qq = 0; qq < 2; qq++)
            GLDS16(Kb + (size_t)(w * 32 + qq * 16 + lrow) * HD + h * 32 + lkof,
                   &KV[0][0][h * 4096 + (w * 32 + qq * 16) * 32]);
    #pragma unroll
    for (int kg = 0; kg < 4; kg++)
        GLDS16(Vtb + (size_t)(w * 16 + lrow) * SEQ + kg * 32 + lkof,
               &KV[0][1][kg * 2048 + (w * 16) * 32]);
    __syncthreads();   // all prologue staging visible

    // ---- hoist Q fragments to registers (loop-invariant) ----
    bf16x8 qf[2][2];   // [half][mi]
    #pragma unroll
    for (int h = 0; h < 2; h++)
        #pragma unroll
        for (int mi = 0; mi < 2; mi++)
            qf[h][mi] = *(const bf16x8*)&Qst[h * 4096 +
                          (w * 32 + mi * 16 + l15) * 32 + qsw];
    __syncthreads();   // Q reads done before kt=0 prefetch overwrites KV[1]

    float l_i[2] = {0.0f, 0.0f};   // per-lane partials; reduced in epilogue
    f32x4 o[2][4];
    #pragma unroll
    for (int mi = 0; mi < 2; mi++)
        #pragma unroll
        for (int db = 0; db < 4; db++) o[mi][db] = (f32x4)0.0f;

    constexpr int NT = SEQ / 128;   // 16 key tiles of 128
    for (int kt = 0; kt < NT; kt++) {
        const int cur = kt & 1, nxt = cur ^ 1;
        if (kt + 1 < NT) {
            const int k0n = (kt + 1) * 128;
            #pragma unroll
            for (int h = 0; h < 2; h++)
                #pragma unroll
                for (int qq = 0; qq < 2; qq++)
                    GLDS16(Kb + (size_t)(k0n + w * 32 + qq * 16 + lrow) * HD + h * 32 + lkof,
                           &KV[nxt][0][h * 4096 + (w * 32 + qq * 16) * 32]);
            #pragma unroll
            for (int kg = 0; kg < 4; kg++)
                GLDS16(Vtb + (size_t)(w * 16 + lrow) * SEQ + k0n + kg * 32 + lkof,
                       &KV[nxt][1][kg * 2048 + (w * 16) * 32]);
        }
        const __bf16* Ks = &KV[cur][0][0];
        const __bf16* Vs = &KV[cur][1][0];

        // ---- T15: QK^T for BOTH 64-key sub-phases up front ----
        f32x4 st[2][2][4];   // [sub][mi][kb], fully unrolled (static idx)
        #pragma unroll
        for (int sub = 0; sub < 2; sub++)
            #pragma unroll
            for (int mi = 0; mi < 2; mi++)
                #pragma unroll
                for (int kb = 0; kb < 4; kb++) st[sub][mi][kb] = (f32x4)0.0f;
        __builtin_amdgcn_s_setprio(1);
        #pragma unroll
        for (int sub = 0; sub < 2; sub++)
            #pragma unroll
            for (int h = 0; h < 2; h++)
                #pragma unroll
                for (int kb = 0; kb < 4; kb++) {
                    const bf16x8 kf = *(const bf16x8*)&Ks[h * 4096 +
                                          (sub * 64 + kb * 16 + l15) * 32 + qsw];
                    #pragma unroll
                    for (int mi = 0; mi < 2; mi++)
                        st[sub][mi][kb] = MFMA16(kf, qf[h][mi], st[sub][mi][kb]);
                }
        __builtin_amdgcn_s_setprio(0);

        // ---- per sub-phase: softmax -> Pt -> PV (SM0 hides under QK1
        // results arriving; SM1 hides under PV0 execution) ----
        #pragma unroll
        for (int sub = 0; sub < 2; sub++) {
            #pragma unroll
            for (int mi = 0; mi < 2; mi++) {
                float rs = 0.0f;
                #pragma unroll
                for (int kb = 0; kb < 4; kb++)
                    #pragma unroll
                    for (int r = 0; r < 4; r++) {
                        const float p = EXP2(st[sub][mi][kb][r]);
                        st[sub][mi][kb][r] = p;
                        rs += p;
                    }
                l_i[mi] += rs;   // lane-partial; quad-reduced in epilogue
                #pragma unroll
                for (int kb = 0; kb < 4; kb++) {
                    __bf16 pb[4] = {(__bf16)st[sub][mi][kb][0], (__bf16)st[sub][mi][kb][1],
                                    (__bf16)st[sub][mi][kb][2], (__bf16)st[sub][mi][kb][3]};
                    // elem off = kb*16 + quad*4; 16B chunk = kb*2+(quad>>1)
                    const int pc = ((kb * 2 + (quad >> 1)) ^ pkey) * 8 + (quad & 1) * 4;
                    *(uint2*)&Pt[w][mi * 16 + l15][pc] = *(uint2*)pb;
                }
            }

            #pragma unroll
            for (int kh = 0; kh < 2; kh++) {
                bf16x8 pf[2];
                #pragma unroll
                for (int mi = 0; mi < 2; mi++) {
                    // elem off = kh*32 + quad*8; chunk = kh*4+quad
                    const int pc = ((kh * 4 + quad) ^ pkey) * 8;
                    pf[mi] = *(const bf16x8*)&Pt[w][mi * 16 + l15][pc];
                }
                __builtin_amdgcn_s_setprio(1);
                #pragma unroll
                for (int db = 0; db < 4; db++) {
                    const bf16x8 vf = *(const bf16x8*)&Vs[(sub * 2 + kh) * 2048 +
                                          (db * 16 + l15) * 32 + qsw];
                    #pragma unroll
                    for (int mi = 0; mi < 2; mi++)
                        o[mi][db] = MFMA16(vf, pf[mi], o[mi][db]);
                }
                __builtin_amdgcn_s_setprio(0);
            }
        }

        __syncthreads();   // single barrier per 128 keys
    }

    // ---- epilogue: reduce l, normalize, subtract-projection, store ----
    const float xs = xsa[0];
    const int b = bh >> 4, h = bh & (NH - 1);
    const __bf16* Vb = V + (size_t)bh * SEQ * HD;
    #pragma unroll
    for (int mi = 0; mi < 2; mi++) {
        l_i[mi] += __shfl_xor(l_i[mi], 16);
        l_i[mi] += __shfl_xor(l_i[mi], 32);
        const int q = q0 + w * 32 + mi * 16 + l15;   // sequence position
        const float inv = 1.0f / l_i[mi];
        float vv[4][4], on[4][4];
        float dp = 0.0f, nn = 0.0f;
        #pragma unroll
        for (int db = 0; db < 4; db++) {
            __bf16 vb4[4];
            *(uint2*)vb4 = *(const uint2*)&Vb[(size_t)q * HD + db * 16 + quad * 4];
            #pragma unroll
            for (int r = 0; r < 4; r++) {
                const float vf = (float)vb4[r];
                const float of = o[mi][db][r] * inv;
                vv[db][r] = vf;
                on[db][r] = of;
                dp += of * vf;
                nn += vf * vf;
            }
        }
        dp += __shfl_xor(dp, 16); dp += __shfl_xor(dp, 32);
        nn += __shfl_xor(nn, 16); nn += __shfl_xor(nn, 32);
        const float coef = xs * dp / (nn + 1e-8f);
        #pragma unroll
        for (int db = 0; db < 4; db++) {
            __bf16 ob[4];
            #pragma unroll
            for (int r = 0; r < 4; r++)
                ob[r] = (__bf16)(on[db][r] - coef * vv[db][r]);
            *(uint2*)&X2[((size_t)b * SEQ + q) * DM + h * HD + db * 16 + quad * 4] =
                *(uint2*)ob;
        }
    }
}

// ======================================================================
extern "C" void kernel_launch(void* const* d_in, const int* in_sizes, int n_in,
                              void* d_out, int out_size, void* d_ws, size_t ws_size,
                              hipStream_t stream)
{
    (void)in_sizes; (void)n_in; (void)out_size; (void)ws_size;
    const float* x   = (const float*)d_in[0];
    const float* Wq  = (const float*)d_in[1];
    const float* Wk  = (const float*)d_in[2];
    const float* Wv  = (const float*)d_in[3];
    const float* Wo  = (const float*)d_in[4];
    const float* xsa = (const float*)d_in[5];
    float* out = (float*)d_out;

    // workspace layout (bf16 elements): 56 MB total
    __bf16* xb  = (__bf16*)d_ws;        // 4 M
    __bf16* Wb  = xb  + NEL;            // 4 x 1 M (Wq,Wk,Wv,Wo)
    __bf16* Qb  = Wb  + 4 * WEL;        // 4 M  (B,H,S,HD), pre-scaled
    __bf16* Kb  = Qb  + NEL;            // 4 M
    __bf16* Vb  = Kb  + NEL;            // 4 M
    __bf16* Vtb = Vb  + NEL;            // 4 M  (B,H,HD,S)
    __bf16* X2  = Vtb + NEL;            // 4 M  (B,S,DM)

    // all fp32->bf16 conversions in one launch
    cvt_all<<<dim3(8192), 256, 0, stream>>>(x, Wq, Wk, Wv, Wo, xb, Wb);

    // Q/K/V projections (V transposed to Vt via LDS; Q pre-scaled)
    // 1D XCD-pinned grid: 8 xcd * 8 x * 12 (z,yq) = 768 blocks
    gemm_nt_mfma<128, 3><<<dim3(768), 256, 0, stream>>>(
        xb, Wb, Qb, Vtb, 1);

    // attention + fused subtract-projection -> X2 (1D XCD-pinned grid,
    // 128q / 4-wave blocks, KVBLK=128, T15 double-pipeline)
    attn_mfma<<<dim3((SEQ / 128) * BATCH * NH), 256, 0, stream>>>(
        Qb, Kb, Vtb, Vb, xsa, X2);

    // output projection, fp32 out; 1D XCD-pinned grid: 8*16*4 = 512 blocks
    gemm_nt_mfma<64, 1><<<dim3(512), 256, 0, stream>>>(
        X2, Wb + 3 * WEL, out, nullptr, 0);
}

// Round 11
// 179.696 us; speedup vs baseline: 1.0329x; 1.0329x over previous
//
#include <hip/hip_runtime.h>
#include <math.h>

// Problem constants
#define BATCH 2
#define SEQ   2048
#define NH    16
#define HD    64
#define DM    1024
#define MROWS (BATCH * SEQ)                  // 4096
#define NEL   ((size_t)MROWS * DM)           // 4 M elements (activation buffer)
#define WEL   ((size_t)DM * DM)              // 1 M elements (weight buffer)
// softmax scale folded into Q at projection: 1/sqrt(64) * log2(e)
#define SM_SCALE_LOG2E 0.18033688011112042f

typedef __bf16 bf16x8 __attribute__((ext_vector_type(8)));
typedef float  f32x4  __attribute__((ext_vector_type(4)));

#define MFMA16(a, b, c) __builtin_amdgcn_mfma_f32_16x16x32_bf16((a), (b), (c), 0, 0, 0)
#define EXP2(x) __builtin_amdgcn_exp2f(x)

// async global->LDS, 16B per lane; LDS dest = wave-uniform base + lane*16
#define GLDS16(g, s) __builtin_amdgcn_global_load_lds( \
    (const __attribute__((address_space(1))) void*)(g), \
    (__attribute__((address_space(3))) void*)(s), 16, 0, 0)

// ----------------------------------------------------------------------
// Verified levers: K/V/Q k-chunk swizzle (R2), Pt chunk^row swizzle (R3),
// XCD pinning attn (R3) + GEMMs (R7), KVBLK=128+deferred l_i (R5),
// Vt LDS-transpose (R6).
// Null/regressed (attn schedule space exhausted): 2-wave blocks (R4),
// 8-wave blocks (R8), counted-vmcnt triple-buffer (R9), T15 QK-hoist
// (R10). R7 = measured optimum (178.7us, attn 52.4us).
// R11: exact R7 revert + __launch_bounds__(256,3) on the GEMM to
// guarantee 3 blocks/CU residency for the 768-block QKV launch (VGPR
// cap 170 >> the ~120 this kernel needs; insurance, no downside).
// ----------------------------------------------------------------------

// ======================================================================
// fp32 -> bf16 convert, single launch: blocks [0,4096) convert x,
// blocks [4096,8192) convert the 4 weight matrices.
// ======================================================================
__global__ __launch_bounds__(256) void cvt_all(
    const float* __restrict__ x,
    const float* __restrict__ w0, const float* __restrict__ w1,
    const float* __restrict__ w2, const float* __restrict__ w3,
    __bf16* __restrict__ xb, __bf16* __restrict__ wb)
{
    const int bid = blockIdx.x;
    const float* src;
    __bf16* dst;
    size_t base;
    if (bid < 4096) {
        src = x; dst = xb; base = (size_t)bid * 1024;
    } else {
        const int r = bid - 4096;
        const int z = r >> 10;
        src = (z == 0) ? w0 : (z == 1) ? w1 : (z == 2) ? w2 : w3;
        dst = wb + (size_t)z * WEL;
        base = (size_t)(r & 1023) * 1024;
    }
    const size_t i = base + (size_t)threadIdx.x * 4;
    const float4 f = *(const float4*)&src[i];
    __bf16 b[4] = {(__bf16)f.x, (__bf16)f.y, (__bf16)f.z, (__bf16)f.w};
    *(ushort4*)&dst[i] = *(ushort4*)b;
}

// ======================================================================
// NT bf16 MFMA GEMM, single-barrier double-buffered K-loop.
// C[m,n] = sum_k A[m,k]*W[n,k]. Tile 128 x BN, BK=32, 4 waves.
// 1D XCD-pinned grid: id -> (xcd=id&7, x, z, yq), y = xcd*4+yq.
// LDS k-chunk XOR-swizzled -> conflict-free b128 fragment reads.
// NZ=3 (BN=128, mode 1): z selects weight+output slab; bf16 store
//   permuted to (B,H,S,HD); z==0 (Q) pre-scaled; z==2 (V) additionally
//   transposed through LDS and stored coalesced to Vt (B,H,HD,S).
// NZ=1 (mode 0): fp32 row-major M x DM store.
// __launch_bounds__(256,3): cap VGPR at 170 so the 768-block QKV grid
//   gets its 3 blocks/CU (acc needs 64 VGPR; ~120 total expected).
// ======================================================================
template<int BN, int NZ>
__global__ __launch_bounds__(256, 3) void gemm_nt_mfma(
    const __bf16* __restrict__ A, const __bf16* __restrict__ W0,
    void* __restrict__ C0, __bf16* __restrict__ Vt, int mode)
{
    constexpr int NI  = BN / 32;         // 16-col groups per wave
    constexpr int NIT = DM / 32;         // 32 K-iterations
    constexpr int NX  = DM / BN;         // 8 (BN=128) or 16 (BN=64)
    constexpr int LNX = (BN == 128) ? 3 : 4;
    // flat LDS: A dbuf (2x4096) + B dbuf (2x BN*32); for BN=128 the whole
    // 16384-elem pool is reused as the 128x128 transpose buffer T.
    __shared__ __bf16 lds[2 * 128 * 32 + 2 * BN * 32];
    #define AST(buf) (lds + (buf) * 4096)
    #define BST(buf) (lds + 8192 + (buf) * (BN * 32))

    const int t = threadIdx.x;
    const int w = t >> 6, l = t & 63;
    const int quad = l >> 4, l15 = l & 15;

    // XCD-pinned decomposition (bijective: 8 * NX * 4*NZ blocks)
    const int id  = blockIdx.x;
    const int xcd = id & 7;
    const int g   = id >> 3;
    const int x   = g & (NX - 1);
    const int r0  = g >> LNX;            // [0, 4*NZ)
    const int z   = r0 >> 2;
    const int yq  = r0 & 3;
    const int y   = xcd * 4 + yq;
    const int m0 = y * 128, n0 = x * BN;
    const int wm = (w >> 1) * 64, wn = (w & 1) * (BN / 2);

    const __bf16* Wp = W0 + (size_t)z * WEL;

    const int lrow = l >> 2;           // staging: lane row within 16-row instr
    // staging k-offset: pre-swizzled global source column (rule #21)
    const int lkof = ((l & 3) ^ ((lrow >> 1) & 3)) * 8;
    // read-side swizzled k-chunk (row bits 1..2 == l15 bits 1..2)
    const int qsw = (quad ^ ((l15 >> 1) & 3)) * 8;

    const __bf16* Ag = A + (size_t)(m0 + w * 32 + lrow) * DM + lkof;
    const int aoff = (w * 32) * 32;    // wave-uniform LDS offset (A)
    // B staging: BN=128 -> 2 instrs/wave (rows w*32); BN=64 -> 1 (rows w*16)
    const int brow = (BN == 128) ? (w * 32) : (w * 16);
    const __bf16* Bg = Wp + (size_t)(n0 + brow + lrow) * DM + lkof;
    const int boff = brow * 32;

    f32x4 acc[4][NI];
    #pragma unroll
    for (int i = 0; i < 4; i++)
        #pragma unroll
        for (int j = 0; j < NI; j++) acc[i][j] = (f32x4)0.0f;

    // prologue: tile 0 -> buf 0
    GLDS16(Ag,           AST(0) + aoff);
    GLDS16(Ag + 16 * DM, AST(0) + aoff + 512);
    GLDS16(Bg,           BST(0) + boff);
    if (BN == 128) GLDS16(Bg + 16 * DM, BST(0) + boff + 512);
    __syncthreads();

    for (int i = 0; i < NIT; i++) {
        const int cur = i & 1, nxt = cur ^ 1;
        if (i + 1 < NIT) {
            const int k0 = (i + 1) * 32;
            GLDS16(Ag + k0,           AST(nxt) + aoff);
            GLDS16(Ag + k0 + 16 * DM, AST(nxt) + aoff + 512);
            GLDS16(Bg + k0,           BST(nxt) + boff);
            if (BN == 128) GLDS16(Bg + k0 + 16 * DM, BST(nxt) + boff + 512);
        }

        bf16x8 af[4], bfr[NI];
        #pragma unroll
        for (int mi = 0; mi < 4; mi++)
            af[mi] = *(const bf16x8*)&AST(cur)[(wm + mi * 16 + l15) * 32 + qsw];
        #pragma unroll
        for (int ni = 0; ni < NI; ni++)
            bfr[ni] = *(const bf16x8*)&BST(cur)[(wn + ni * 16 + l15) * 32 + qsw];
        __builtin_amdgcn_s_setprio(1);
        #pragma unroll
        for (int mi = 0; mi < 4; mi++)
            #pragma unroll
            for (int ni = 0; ni < NI; ni++)
                acc[mi][ni] = MFMA16(af[mi], bfr[ni], acc[mi][ni]);
        __builtin_amdgcn_s_setprio(0);

        __syncthreads();   // single barrier: drains prefetch, fences buffers
    }

    if (mode) {
        const float sc = (z == 0) ? SM_SCALE_LOG2E : 1.0f;
        __bf16* C = (__bf16*)C0 + (size_t)z * NEL;
        #pragma unroll
        for (int mi = 0; mi < 4; mi++)
            #pragma unroll
            for (int ni = 0; ni < NI; ni++)
                #pragma unroll
                for (int r = 0; r < 4; r++) {
                    const int row = m0 + wm + mi * 16 + quad * 4 + r;
                    const int col = n0 + wn + ni * 16 + l15;
                    const int b = row >> 11, s = row & (SEQ - 1);
                    const int h = col >> 6,  d = col & (HD - 1);
                    const __bf16 val = (__bf16)(acc[mi][ni][r] * sc);
                    C[((size_t)(b * NH + h) * SEQ + s) * HD + d] = val;
                }

        if constexpr (BN == 128) {
            if (z == 2) {
                // ---- Vt via LDS transpose: T[col 128][s 128], 16B-chunk
                // swizzle sc^(col&7). acc r-values are s-consecutive ->
                // one 8B packed write per (mi,ni).
                __bf16* T = lds;   // staging buffers dead after final barrier
                #pragma unroll
                for (int mi = 0; mi < 4; mi++)
                    #pragma unroll
                    for (int ni = 0; ni < 4; ni++) {
                        const int cl = wn + ni * 16 + l15;
                        const int s0 = wm + mi * 16 + quad * 4;
                        __bf16 pb[4] = {(__bf16)acc[mi][ni][0], (__bf16)acc[mi][ni][1],
                                        (__bf16)acc[mi][ni][2], (__bf16)acc[mi][ni][3]};
                        const int scn = s0 >> 3;          // 16B chunk along s
                        const int sub = (s0 >> 2) & 1;    // 8B half
                        *(uint2*)&T[cl * 128 + ((scn ^ (cl & 7)) * 8) + sub * 4] =
                            *(uint2*)pb;
                    }
                __syncthreads();
                // read back coalesced: per instr, 8 cols x 8 consecutive
                // 16B chunks (128B runs) -> uint4 stores to Vt
                const int b = m0 >> 11;
                const int sbase = m0 & (SEQ - 1);
                #pragma unroll
                for (int u = 0; u < 8; u++) {
                    const int cl = ((u >> 1) * 32) + (t >> 3);
                    const int ci = (u & 1) * 8 + (t & 7);
                    const int hh = (n0 + cl) >> 6, dd = (n0 + cl) & (HD - 1);
                    const uint4 v = *(const uint4*)&T[cl * 128 + ((ci ^ (cl & 7)) * 8)];
                    *(uint4*)&Vt[((size_t)(b * NH + hh) * HD + dd) * SEQ +
                                 sbase + ci * 8] = v;
                }
            }
        }
    } else {
        float* C = (float*)C0;
        #pragma unroll
        for (int mi = 0; mi < 4; mi++)
            #pragma unroll
            for (int ni = 0; ni < NI; ni++)
                #pragma unroll
                for (int r = 0; r < 4; r++) {
                    const int row = m0 + wm + mi * 16 + quad * 4 + r;
                    const int col = n0 + wn + ni * 16 + l15;
                    C[(size_t)row * DM + col] = acc[mi][ni][r];
                }
    }
    #undef AST
    #undef BST
}

// ======================================================================
// Flash attention v8 (R7 exact): 4-wave/128q, KVBLK=128, double-buffered
// K/V, deferred l_i, XCD-pinned 1D grid, swizzled K/V/Q + Pt, setprio.
// LDS: KV dbuf 2 x 32 KB + Pt 16 KB = 80 KB -> 2 blocks/CU (grid 512).
// ======================================================================
__global__ __launch_bounds__(256, 2) void attn_mfma(
    const __bf16* __restrict__ Q, const __bf16* __restrict__ K,
    const __bf16* __restrict__ Vt, const __bf16* __restrict__ V,
    const float* __restrict__ xsa, __bf16* __restrict__ X2)
{
    // KV[buf][0] = K region [h][key128][32]  (h*4096 + key*32 + j)
    // KV[buf][1] = V region [kg][dim64][32]  (kg*2048 + dim*32 + j), kg=key/32
    __shared__ __bf16 KV[2][2][8192];
    __shared__ __bf16 Pt[4][32][64];   // per-wave P [q][key64], XOR-swizzled

    const int t = threadIdx.x;
    const int w = t >> 6, l = t & 63;
    const int quad = l >> 4, l15 = l & 15;
    // XCD-pinned decomposition: id%8 == bh%8 -> one XCD per (b,h)
    const int bh = blockIdx.x & 31;
    const int q0 = (blockIdx.x >> 5) * 128;

    const __bf16* Qb  = Q  + (size_t)bh * SEQ * HD;
    const __bf16* Kb  = K  + (size_t)bh * SEQ * HD;
    const __bf16* Vtb = Vt + (size_t)bh * HD * SEQ;

    const int lrow = l >> 2;
    // staging k-offset: pre-swizzled global source column (rule #21)
    const int lkof = ((l & 3) ^ ((lrow >> 1) & 3)) * 8;
    // read-side swizzled k-chunk
    const int qsw = (quad ^ ((l15 >> 1) & 3)) * 8;
    // Pt swizzle key: row & 7 == l15 & 7 for all Pt accesses
    const int pkey = l15 & 7;

    // ---- prologue: stage Q into KV[1][0] (16 KB overlay) + K0/V0 -> KV[0]
    __bf16* Qst = &KV[1][0][0];   // flat [h][q128][32]: h*4096 + q*32 + j
    #pragma unroll
    for (int h = 0; h < 2; h++)
        #pragma unroll
        for (int qq = 0; qq < 2; qq++)
            GLDS16(Qb + (size_t)(q0 + w * 32 + qq * 16 + lrow) * HD + h * 32 + lkof,
                   Qst + h * 4096 + (w * 32 + qq * 16) * 32);
    #pragma unroll
    for (int h = 0; h < 2; h++)
        #pragma unroll
        for (int qq = 0; qq < 2; qq++)
            GLDS16(Kb + (size_t)(w * 32 + qq * 16 + lrow) * HD + h * 32 + lkof,
                   &KV[0][0][h * 4096 + (w * 32 + qq * 16) * 32]);
    #pragma unroll
    for (int kg = 0; kg < 4; kg++)
        GLDS16(Vtb + (size_t)(w * 16 + lrow) * SEQ + kg * 32 + lkof,
               &KV[0][1][kg * 2048 + (w * 16) * 32]);
    __syncthreads();   // all prologue staging visible

    // ---- hoist Q fragments to registers (loop-invariant) ----
    bf16x8 qf[2][2];   // [half][mi]
    #pragma unroll
    for (int h = 0; h < 2; h++)
        #pragma unroll
        for (int mi = 0; mi < 2; mi++)
            qf[h][mi] = *(const bf16x8*)&Qst[h * 4096 +
                          (w * 32 + mi * 16 + l15) * 32 + qsw];
    __syncthreads();   // Q reads done before kt=0 prefetch overwrites KV[1]

    float l_i[2] = {0.0f, 0.0f};   // per-lane partials; reduced in epilogue
    f32x4 o[2][4];
    #pragma unroll
    for (int mi = 0; mi < 2; mi++)
        #pragma unroll
        for (int db = 0; db < 4; db++) o[mi][db] = (f32x4)0.0f;

    constexpr int NT = SEQ / 128;   // 16 key tiles of 128
    for (int kt = 0; kt < NT; kt++) {
        const int cur = kt & 1, nxt = cur ^ 1;
        if (kt + 1 < NT) {
            const int k0n = (kt + 1) * 128;
            #pragma unroll
            for (int h = 0; h < 2; h++)
                #pragma unroll
                for (int qq = 0; qq < 2; qq++)
                    GLDS16(Kb + (size_t)(k0n + w * 32 + qq * 16 + lrow) * HD + h * 32 + lkof,
                           &KV[nxt][0][h * 4096 + (w * 32 + qq * 16) * 32]);
            #pragma unroll
            for (int kg = 0; kg < 4; kg++)
                GLDS16(Vtb + (size_t)(w * 16 + lrow) * SEQ + k0n + kg * 32 + lkof,
                       &KV[nxt][1][kg * 2048 + (w * 16) * 32]);
        }
        const __bf16* Ks = &KV[cur][0][0];
        const __bf16* Vs = &KV[cur][1][0];

        // two 64-key sub-phases; per-wave Pt reused with no block sync
        #pragma unroll
        for (int sub = 0; sub < 2; sub++) {
            // ---- S^T = K Q^T : 64k x 32q x 64d per wave (16 MFMAs) ----
            f32x4 st[2][4];
            #pragma unroll
            for (int mi = 0; mi < 2; mi++)
                #pragma unroll
                for (int kb = 0; kb < 4; kb++) st[mi][kb] = (f32x4)0.0f;
            __builtin_amdgcn_s_setprio(1);
            #pragma unroll
            for (int h = 0; h < 2; h++)
                #pragma unroll
                for (int kb = 0; kb < 4; kb++) {
                    const bf16x8 kf = *(const bf16x8*)&Ks[h * 4096 +
                                          (sub * 64 + kb * 16 + l15) * 32 + qsw];
                    #pragma unroll
                    for (int mi = 0; mi < 2; mi++)
                        st[mi][kb] = MFMA16(kf, qf[h][mi], st[mi][kb]);
                }
            __builtin_amdgcn_s_setprio(0);

            // ---- fixed-shift softmax: p = exp2(s), per-lane l partial ----
            #pragma unroll
            for (int mi = 0; mi < 2; mi++) {
                float rs = 0.0f;
                #pragma unroll
                for (int kb = 0; kb < 4; kb++)
                    #pragma unroll
                    for (int r = 0; r < 4; r++) {
                        const float p = EXP2(st[mi][kb][r]);
                        st[mi][kb][r] = p;
                        rs += p;
                    }
                l_i[mi] += rs;   // lane-partial; quad-reduced in epilogue
                #pragma unroll
                for (int kb = 0; kb < 4; kb++) {
                    __bf16 pb[4] = {(__bf16)st[mi][kb][0], (__bf16)st[mi][kb][1],
                                    (__bf16)st[mi][kb][2], (__bf16)st[mi][kb][3]};
                    // elem off = kb*16 + quad*4; 16B chunk = kb*2+(quad>>1)
                    const int pc = ((kb * 2 + (quad >> 1)) ^ pkey) * 8 + (quad & 1) * 4;
                    *(uint2*)&Pt[w][mi * 16 + l15][pc] = *(uint2*)pb;
                }
            }

            // ---- O^T += V^T P^T : 64d x 32q x 64k per wave (16 MFMAs) ----
            #pragma unroll
            for (int kh = 0; kh < 2; kh++) {
                bf16x8 pf[2];
                #pragma unroll
                for (int mi = 0; mi < 2; mi++) {
                    // elem off = kh*32 + quad*8; chunk = kh*4+quad
                    const int pc = ((kh * 4 + quad) ^ pkey) * 8;
                    pf[mi] = *(const bf16x8*)&Pt[w][mi * 16 + l15][pc];
                }
                __builtin_amdgcn_s_setprio(1);
                #pragma unroll
                for (int db = 0; db < 4; db++) {
                    const bf16x8 vf = *(const bf16x8*)&Vs[(sub * 2 + kh) * 2048 +
                                          (db * 16 + l15) * 32 + qsw];
                    #pragma unroll
                    for (int mi = 0; mi < 2; mi++)
                        o[mi][db] = MFMA16(vf, pf[mi], o[mi][db]);
                }
                __builtin_amdgcn_s_setprio(0);
            }
        }

        __syncthreads();   // single barrier per 128 keys
    }

    // ---- epilogue: reduce l, normalize, subtract-projection, store ----
    const float xs = xsa[0];
    const int b = bh >> 4, h = bh & (NH - 1);
    const __bf16* Vb = V + (size_t)bh * SEQ * HD;
    #pragma unroll
    for (int mi = 0; mi < 2; mi++) {
        l_i[mi] += __shfl_xor(l_i[mi], 16);
        l_i[mi] += __shfl_xor(l_i[mi], 32);
        const int q = q0 + w * 32 + mi * 16 + l15;   // sequence position
        const float inv = 1.0f / l_i[mi];
        float vv[4][4], on[4][4];
        float dp = 0.0f, nn = 0.0f;
        #pragma unroll
        for (int db = 0; db < 4; db++) {
            __bf16 vb4[4];
            *(uint2*)vb4 = *(const uint2*)&Vb[(size_t)q * HD + db * 16 + quad * 4];
            #pragma unroll
            for (int r = 0; r < 4; r++) {
                const float vf = (float)vb4[r];
                const float of = o[mi][db][r] * inv;
                vv[db][r] = vf;
                on[db][r] = of;
                dp += of * vf;
                nn += vf * vf;
            }
        }
        dp += __shfl_xor(dp, 16); dp += __shfl_xor(dp, 32);
        nn += __shfl_xor(nn, 16); nn += __shfl_xor(nn, 32);
        const float coef = xs * dp / (nn + 1e-8f);
        #pragma unroll
        for (int db = 0; db < 4; db++) {
            __bf16 ob[4];
            #pragma unroll
            for (int r = 0; r < 4; r++)
                ob[r] = (__bf16)(on[db][r] - coef * vv[db][r]);
            *(uint2*)&X2[((size_t)b * SEQ + q) * DM + h * HD + db * 16 + quad * 4] =
                *(uint2*)ob;
        }
    }
}

// ======================================================================
extern "C" void kernel_launch(void* const* d_in, const int* in_sizes, int n_in,
                              void* d_out, int out_size, void* d_ws, size_t ws_size,
                              hipStream_t stream)
{
    (void)in_sizes; (void)n_in; (void)out_size; (void)ws_size;
    const float* x   = (const float*)d_in[0];
    const float* Wq  = (const float*)d_in[1];
    const float* Wk  = (const float*)d_in[2];
    const float* Wv  = (const float*)d_in[3];
    const float* Wo  = (const float*)d_in[4];
    const float* xsa = (const float*)d_in[5];
    float* out = (float*)d_out;

    // workspace layout (bf16 elements): 56 MB total
    __bf16* xb  = (__bf16*)d_ws;        // 4 M
    __bf16* Wb  = xb  + NEL;            // 4 x 1 M (Wq,Wk,Wv,Wo)
    __bf16* Qb  = Wb  + 4 * WEL;        // 4 M  (B,H,S,HD), pre-scaled
    __bf16* Kb  = Qb  + NEL;            // 4 M
    __bf16* Vb  = Kb  + NEL;            // 4 M
    __bf16* Vtb = Vb  + NEL;            // 4 M  (B,H,HD,S)
    __bf16* X2  = Vtb + NEL;            // 4 M  (B,S,DM)

    // all fp32->bf16 conversions in one launch
    cvt_all<<<dim3(8192), 256, 0, stream>>>(x, Wq, Wk, Wv, Wo, xb, Wb);

    // Q/K/V projections (V transposed to Vt via LDS; Q pre-scaled)
    // 1D XCD-pinned grid: 8 xcd * 8 x * 12 (z,yq) = 768 blocks
    gemm_nt_mfma<128, 3><<<dim3(768), 256, 0, stream>>>(
        xb, Wb, Qb, Vtb, 1);

    // attention + fused subtract-projection -> X2 (1D XCD-pinned grid,
    // 128q / 4-wave blocks, KVBLK=128)
    attn_mfma<<<dim3((SEQ / 128) * BATCH * NH), 256, 0, stream>>>(
        Qb, Kb, Vtb, Vb, xsa, X2);

    // output projection, fp32 out; 1D XCD-pinned grid: 8*16*4 = 512 blocks
    gemm_nt_mfma<64, 1><<<dim3(512), 256, 0, stream>>>(
        X2, Wb + 3 * WEL, out, nullptr, 0);
}

// Round 12
// 177.409 us; speedup vs baseline: 1.0462x; 1.0129x over previous
//
#include <hip/hip_runtime.h>
#include <math.h>

// Problem constants
#define BATCH 2
#define SEQ   2048
#define NH    16
#define HD    64
#define DM    1024
#define MROWS (BATCH * SEQ)                  // 4096
#define NEL   ((size_t)MROWS * DM)           // 4 M elements (activation buffer)
#define WEL   ((size_t)DM * DM)              // 1 M elements (weight buffer)
// softmax scale folded into Q at projection: 1/sqrt(64) * log2(e)
#define SM_SCALE_LOG2E 0.18033688011112042f

typedef __bf16 bf16x8 __attribute__((ext_vector_type(8)));
typedef float  f32x4  __attribute__((ext_vector_type(4)));

#define MFMA16(a, b, c) __builtin_amdgcn_mfma_f32_16x16x32_bf16((a), (b), (c), 0, 0, 0)
#define EXP2(x) __builtin_amdgcn_exp2f(x)

// async global->LDS, 16B per lane; LDS dest = wave-uniform base + lane*16
#define GLDS16(g, s) __builtin_amdgcn_global_load_lds( \
    (const __attribute__((address_space(1))) void*)(g), \
    (__attribute__((address_space(3))) void*)(s), 16, 0, 0)

// ----------------------------------------------------------------------
// Verified levers: K/V/Q k-chunk swizzle (R2), Pt chunk^row swizzle (R3),
// XCD pinning attn (R3) + GEMMs (R7), KVBLK=128+deferred l_i (R5),
// Vt LDS-transpose (R6).
// Null/regressed (schedule space exhausted on this structure): 2-wave
// blocks (R4), 8-wave blocks (R8), counted-vmcnt triple-buffer (R9),
// T15 QK-hoist (R10), GEMM launch-bounds (R11 neutral).
// R12: consolidation at measured optimum (R7/R11 ~178-180us) + X2
// aliased onto xb (dead after QKV; single-stream ordering makes the
// alias safe) -> ws 56->48 MB.
// Remaining documented lever: m201 8-phase 256^2 GEMM port — requires
// the reference example's exact region-phase/vmcnt choreography (blind
// reconstruction hits the m152 race class); not a safe one-shot.
// ----------------------------------------------------------------------

// ======================================================================
// fp32 -> bf16 convert, single launch: blocks [0,4096) convert x,
// blocks [4096,8192) convert the 4 weight matrices.
// ======================================================================
__global__ __launch_bounds__(256) void cvt_all(
    const float* __restrict__ x,
    const float* __restrict__ w0, const float* __restrict__ w1,
    const float* __restrict__ w2, const float* __restrict__ w3,
    __bf16* __restrict__ xb, __bf16* __restrict__ wb)
{
    const int bid = blockIdx.x;
    const float* src;
    __bf16* dst;
    size_t base;
    if (bid < 4096) {
        src = x; dst = xb; base = (size_t)bid * 1024;
    } else {
        const int r = bid - 4096;
        const int z = r >> 10;
        src = (z == 0) ? w0 : (z == 1) ? w1 : (z == 2) ? w2 : w3;
        dst = wb + (size_t)z * WEL;
        base = (size_t)(r & 1023) * 1024;
    }
    const size_t i = base + (size_t)threadIdx.x * 4;
    const float4 f = *(const float4*)&src[i];
    __bf16 b[4] = {(__bf16)f.x, (__bf16)f.y, (__bf16)f.z, (__bf16)f.w};
    *(ushort4*)&dst[i] = *(ushort4*)b;
}

// ======================================================================
// NT bf16 MFMA GEMM, single-barrier double-buffered K-loop.
// C[m,n] = sum_k A[m,k]*W[n,k]. Tile 128 x BN, BK=32, 4 waves.
// 1D XCD-pinned grid: id -> (xcd=id&7, x, z, yq), y = xcd*4+yq.
// LDS k-chunk XOR-swizzled -> conflict-free b128 fragment reads.
// NZ=3 (BN=128, mode 1): z selects weight+output slab; bf16 store
//   permuted to (B,H,S,HD); z==0 (Q) pre-scaled; z==2 (V) additionally
//   transposed through LDS and stored coalesced to Vt (B,H,HD,S).
// NZ=1 (mode 0): fp32 row-major M x DM store.
// ======================================================================
template<int BN, int NZ>
__global__ __launch_bounds__(256, 3) void gemm_nt_mfma(
    const __bf16* __restrict__ A, const __bf16* __restrict__ W0,
    void* __restrict__ C0, __bf16* __restrict__ Vt, int mode)
{
    constexpr int NI  = BN / 32;         // 16-col groups per wave
    constexpr int NIT = DM / 32;         // 32 K-iterations
    constexpr int NX  = DM / BN;         // 8 (BN=128) or 16 (BN=64)
    constexpr int LNX = (BN == 128) ? 3 : 4;
    // flat LDS: A dbuf (2x4096) + B dbuf (2x BN*32); for BN=128 the whole
    // 16384-elem pool is reused as the 128x128 transpose buffer T.
    __shared__ __bf16 lds[2 * 128 * 32 + 2 * BN * 32];
    #define AST(buf) (lds + (buf) * 4096)
    #define BST(buf) (lds + 8192 + (buf) * (BN * 32))

    const int t = threadIdx.x;
    const int w = t >> 6, l = t & 63;
    const int quad = l >> 4, l15 = l & 15;

    // XCD-pinned decomposition (bijective: 8 * NX * 4*NZ blocks)
    const int id  = blockIdx.x;
    const int xcd = id & 7;
    const int g   = id >> 3;
    const int x   = g & (NX - 1);
    const int r0  = g >> LNX;            // [0, 4*NZ)
    const int z   = r0 >> 2;
    const int yq  = r0 & 3;
    const int y   = xcd * 4 + yq;
    const int m0 = y * 128, n0 = x * BN;
    const int wm = (w >> 1) * 64, wn = (w & 1) * (BN / 2);

    const __bf16* Wp = W0 + (size_t)z * WEL;

    const int lrow = l >> 2;           // staging: lane row within 16-row instr
    // staging k-offset: pre-swizzled global source column (rule #21)
    const int lkof = ((l & 3) ^ ((lrow >> 1) & 3)) * 8;
    // read-side swizzled k-chunk (row bits 1..2 == l15 bits 1..2)
    const int qsw = (quad ^ ((l15 >> 1) & 3)) * 8;

    const __bf16* Ag = A + (size_t)(m0 + w * 32 + lrow) * DM + lkof;
    const int aoff = (w * 32) * 32;    // wave-uniform LDS offset (A)
    // B staging: BN=128 -> 2 instrs/wave (rows w*32); BN=64 -> 1 (rows w*16)
    const int brow = (BN == 128) ? (w * 32) : (w * 16);
    const __bf16* Bg = Wp + (size_t)(n0 + brow + lrow) * DM + lkof;
    const int boff = brow * 32;

    f32x4 acc[4][NI];
    #pragma unroll
    for (int i = 0; i < 4; i++)
        #pragma unroll
        for (int j = 0; j < NI; j++) acc[i][j] = (f32x4)0.0f;

    // prologue: tile 0 -> buf 0
    GLDS16(Ag,           AST(0) + aoff);
    GLDS16(Ag + 16 * DM, AST(0) + aoff + 512);
    GLDS16(Bg,           BST(0) + boff);
    if (BN == 128) GLDS16(Bg + 16 * DM, BST(0) + boff + 512);
    __syncthreads();

    for (int i = 0; i < NIT; i++) {
        const int cur = i & 1, nxt = cur ^ 1;
        if (i + 1 < NIT) {
            const int k0 = (i + 1) * 32;
            GLDS16(Ag + k0,           AST(nxt) + aoff);
            GLDS16(Ag + k0 + 16 * DM, AST(nxt) + aoff + 512);
            GLDS16(Bg + k0,           BST(nxt) + boff);
            if (BN == 128) GLDS16(Bg + k0 + 16 * DM, BST(nxt) + boff + 512);
        }

        bf16x8 af[4], bfr[NI];
        #pragma unroll
        for (int mi = 0; mi < 4; mi++)
            af[mi] = *(const bf16x8*)&AST(cur)[(wm + mi * 16 + l15) * 32 + qsw];
        #pragma unroll
        for (int ni = 0; ni < NI; ni++)
            bfr[ni] = *(const bf16x8*)&BST(cur)[(wn + ni * 16 + l15) * 32 + qsw];
        __builtin_amdgcn_s_setprio(1);
        #pragma unroll
        for (int mi = 0; mi < 4; mi++)
            #pragma unroll
            for (int ni = 0; ni < NI; ni++)
                acc[mi][ni] = MFMA16(af[mi], bfr[ni], acc[mi][ni]);
        __builtin_amdgcn_s_setprio(0);

        __syncthreads();   // single barrier: drains prefetch, fences buffers
    }

    if (mode) {
        const float sc = (z == 0) ? SM_SCALE_LOG2E : 1.0f;
        __bf16* C = (__bf16*)C0 + (size_t)z * NEL;
        #pragma unroll
        for (int mi = 0; mi < 4; mi++)
            #pragma unroll
            for (int ni = 0; ni < NI; ni++)
                #pragma unroll
                for (int r = 0; r < 4; r++) {
                    const int row = m0 + wm + mi * 16 + quad * 4 + r;
                    const int col = n0 + wn + ni * 16 + l15;
                    const int b = row >> 11, s = row & (SEQ - 1);
                    const int h = col >> 6,  d = col & (HD - 1);
                    const __bf16 val = (__bf16)(acc[mi][ni][r] * sc);
                    C[((size_t)(b * NH + h) * SEQ + s) * HD + d] = val;
                }

        if constexpr (BN == 128) {
            if (z == 2) {
                // ---- Vt via LDS transpose: T[col 128][s 128], 16B-chunk
                // swizzle sc^(col&7). acc r-values are s-consecutive ->
                // one 8B packed write per (mi,ni).
                __bf16* T = lds;   // staging buffers dead after final barrier
                #pragma unroll
                for (int mi = 0; mi < 4; mi++)
                    #pragma unroll
                    for (int ni = 0; ni < 4; ni++) {
                        const int cl = wn + ni * 16 + l15;
                        const int s0 = wm + mi * 16 + quad * 4;
                        __bf16 pb[4] = {(__bf16)acc[mi][ni][0], (__bf16)acc[mi][ni][1],
                                        (__bf16)acc[mi][ni][2], (__bf16)acc[mi][ni][3]};
                        const int scn = s0 >> 3;          // 16B chunk along s
                        const int sub = (s0 >> 2) & 1;    // 8B half
                        *(uint2*)&T[cl * 128 + ((scn ^ (cl & 7)) * 8) + sub * 4] =
                            *(uint2*)pb;
                    }
                __syncthreads();
                // read back coalesced: per instr, 8 cols x 8 consecutive
                // 16B chunks (128B runs) -> uint4 stores to Vt
                const int b = m0 >> 11;
                const int sbase = m0 & (SEQ - 1);
                #pragma unroll
                for (int u = 0; u < 8; u++) {
                    const int cl = ((u >> 1) * 32) + (t >> 3);
                    const int ci = (u & 1) * 8 + (t & 7);
                    const int hh = (n0 + cl) >> 6, dd = (n0 + cl) & (HD - 1);
                    const uint4 v = *(const uint4*)&T[cl * 128 + ((ci ^ (cl & 7)) * 8)];
                    *(uint4*)&Vt[((size_t)(b * NH + hh) * HD + dd) * SEQ +
                                 sbase + ci * 8] = v;
                }
            }
        }
    } else {
        float* C = (float*)C0;
        #pragma unroll
        for (int mi = 0; mi < 4; mi++)
            #pragma unroll
            for (int ni = 0; ni < NI; ni++)
                #pragma unroll
                for (int r = 0; r < 4; r++) {
                    const int row = m0 + wm + mi * 16 + quad * 4 + r;
                    const int col = n0 + wn + ni * 16 + l15;
                    C[(size_t)row * DM + col] = acc[mi][ni][r];
                }
    }
    #undef AST
    #undef BST
}

// ======================================================================
// Flash attention v8 (R7 exact): 4-wave/128q, KVBLK=128, double-buffered
// K/V, deferred l_i, XCD-pinned 1D grid, swizzled K/V/Q + Pt, setprio.
// LDS: KV dbuf 2 x 32 KB + Pt 16 KB = 80 KB -> 2 blocks/CU (grid 512).
// Structure plateau: latency-bound at 2 waves/SIMD (grid-pinned); all
// catalog schedule levers isolated null here (R4/R8/R9/R10).
// ======================================================================
__global__ __launch_bounds__(256, 2) void attn_mfma(
    const __bf16* __restrict__ Q, const __bf16* __restrict__ K,
    const __bf16* __restrict__ Vt, const __bf16* __restrict__ V,
    const float* __restrict__ xsa, __bf16* __restrict__ X2)
{
    // KV[buf][0] = K region [h][key128][32]  (h*4096 + key*32 + j)
    // KV[buf][1] = V region [kg][dim64][32]  (kg*2048 + dim*32 + j), kg=key/32
    __shared__ __bf16 KV[2][2][8192];
    __shared__ __bf16 Pt[4][32][64];   // per-wave P [q][key64], XOR-swizzled

    const int t = threadIdx.x;
    const int w = t >> 6, l = t & 63;
    const int quad = l >> 4, l15 = l & 15;
    // XCD-pinned decomposition: id%8 == bh%8 -> one XCD per (b,h)
    const int bh = blockIdx.x & 31;
    const int q0 = (blockIdx.x >> 5) * 128;

    const __bf16* Qb  = Q  + (size_t)bh * SEQ * HD;
    const __bf16* Kb  = K  + (size_t)bh * SEQ * HD;
    const __bf16* Vtb = Vt + (size_t)bh * HD * SEQ;

    const int lrow = l >> 2;
    // staging k-offset: pre-swizzled global source column (rule #21)
    const int lkof = ((l & 3) ^ ((lrow >> 1) & 3)) * 8;
    // read-side swizzled k-chunk
    const int qsw = (quad ^ ((l15 >> 1) & 3)) * 8;
    // Pt swizzle key: row & 7 == l15 & 7 for all Pt accesses
    const int pkey = l15 & 7;

    // ---- prologue: stage Q into KV[1][0] (16 KB overlay) + K0/V0 -> KV[0]
    __bf16* Qst = &KV[1][0][0];   // flat [h][q128][32]: h*4096 + q*32 + j
    #pragma unroll
    for (int h = 0; h < 2; h++)
        #pragma unroll
        for (int qq = 0; qq < 2; qq++)
            GLDS16(Qb + (size_t)(q0 + w * 32 + qq * 16 + lrow) * HD + h * 32 + lkof,
                   Qst + h * 4096 + (w * 32 + qq * 16) * 32);
    #pragma unroll
    for (int h = 0; h < 2; h++)
        #pragma unroll
        for (int qq = 0; qq < 2; qq++)
            GLDS16(Kb + (size_t)(w * 32 + qq * 16 + lrow) * HD + h * 32 + lkof,
                   &KV[0][0][h * 4096 + (w * 32 + qq * 16) * 32]);
    #pragma unroll
    for (int kg = 0; kg < 4; kg++)
        GLDS16(Vtb + (size_t)(w * 16 + lrow) * SEQ + kg * 32 + lkof,
               &KV[0][1][kg * 2048 + (w * 16) * 32]);
    __syncthreads();   // all prologue staging visible

    // ---- hoist Q fragments to registers (loop-invariant) ----
    bf16x8 qf[2][2];   // [half][mi]
    #pragma unroll
    for (int h = 0; h < 2; h++)
        #pragma unroll
        for (int mi = 0; mi < 2; mi++)
            qf[h][mi] = *(const bf16x8*)&Qst[h * 4096 +
                          (w * 32 + mi * 16 + l15) * 32 + qsw];
    __syncthreads();   // Q reads done before kt=0 prefetch overwrites KV[1]

    float l_i[2] = {0.0f, 0.0f};   // per-lane partials; reduced in epilogue
    f32x4 o[2][4];
    #pragma unroll
    for (int mi = 0; mi < 2; mi++)
        #pragma unroll
        for (int db = 0; db < 4; db++) o[mi][db] = (f32x4)0.0f;

    constexpr int NT = SEQ / 128;   // 16 key tiles of 128
    for (int kt = 0; kt < NT; kt++) {
        const int cur = kt & 1, nxt = cur ^ 1;
        if (kt + 1 < NT) {
            const int k0n = (kt + 1) * 128;
            #pragma unroll
            for (int h = 0; h < 2; h++)
                #pragma unroll
                for (int qq = 0; qq < 2; qq++)
                    GLDS16(Kb + (size_t)(k0n + w * 32 + qq * 16 + lrow) * HD + h * 32 + lkof,
                           &KV[nxt][0][h * 4096 + (w * 32 + qq * 16) * 32]);
            #pragma unroll
            for (int kg = 0; kg < 4; kg++)
                GLDS16(Vtb + (size_t)(w * 16 + lrow) * SEQ + k0n + kg * 32 + lkof,
                       &KV[nxt][1][kg * 2048 + (w * 16) * 32]);
        }
        const __bf16* Ks = &KV[cur][0][0];
        const __bf16* Vs = &KV[cur][1][0];

        // two 64-key sub-phases; per-wave Pt reused with no block sync
        #pragma unroll
        for (int sub = 0; sub < 2; sub++) {
            // ---- S^T = K Q^T : 64k x 32q x 64d per wave (16 MFMAs) ----
            f32x4 st[2][4];
            #pragma unroll
            for (int mi = 0; mi < 2; mi++)
                #pragma unroll
                for (int kb = 0; kb < 4; kb++) st[mi][kb] = (f32x4)0.0f;
            __builtin_amdgcn_s_setprio(1);
            #pragma unroll
            for (int h = 0; h < 2; h++)
                #pragma unroll
                for (int kb = 0; kb < 4; kb++) {
                    const bf16x8 kf = *(const bf16x8*)&Ks[h * 4096 +
                                          (sub * 64 + kb * 16 + l15) * 32 + qsw];
                    #pragma unroll
                    for (int mi = 0; mi < 2; mi++)
                        st[mi][kb] = MFMA16(kf, qf[h][mi], st[mi][kb]);
                }
            __builtin_amdgcn_s_setprio(0);

            // ---- fixed-shift softmax: p = exp2(s), per-lane l partial ----
            #pragma unroll
            for (int mi = 0; mi < 2; mi++) {
                float rs = 0.0f;
                #pragma unroll
                for (int kb = 0; kb < 4; kb++)
                    #pragma unroll
                    for (int r = 0; r < 4; r++) {
                        const float p = EXP2(st[mi][kb][r]);
                        st[mi][kb][r] = p;
                        rs += p;
                    }
                l_i[mi] += rs;   // lane-partial; quad-reduced in epilogue
                #pragma unroll
                for (int kb = 0; kb < 4; kb++) {
                    __bf16 pb[4] = {(__bf16)st[mi][kb][0], (__bf16)st[mi][kb][1],
                                    (__bf16)st[mi][kb][2], (__bf16)st[mi][kb][3]};
                    // elem off = kb*16 + quad*4; 16B chunk = kb*2+(quad>>1)
                    const int pc = ((kb * 2 + (quad >> 1)) ^ pkey) * 8 + (quad & 1) * 4;
                    *(uint2*)&Pt[w][mi * 16 + l15][pc] = *(uint2*)pb;
                }
            }

            // ---- O^T += V^T P^T : 64d x 32q x 64k per wave (16 MFMAs) ----
            #pragma unroll
            for (int kh = 0; kh < 2; kh++) {
                bf16x8 pf[2];
                #pragma unroll
                for (int mi = 0; mi < 2; mi++) {
                    // elem off = kh*32 + quad*8; chunk = kh*4+quad
                    const int pc = ((kh * 4 + quad) ^ pkey) * 8;
                    pf[mi] = *(const bf16x8*)&Pt[w][mi * 16 + l15][pc];
                }
                __builtin_amdgcn_s_setprio(1);
                #pragma unroll
                for (int db = 0; db < 4; db++) {
                    const bf16x8 vf = *(const bf16x8*)&Vs[(sub * 2 + kh) * 2048 +
                                          (db * 16 + l15) * 32 + qsw];
                    #pragma unroll
                    for (int mi = 0; mi < 2; mi++)
                        o[mi][db] = MFMA16(vf, pf[mi], o[mi][db]);
                }
                __builtin_amdgcn_s_setprio(0);
            }
        }

        __syncthreads();   // single barrier per 128 keys
    }

    // ---- epilogue: reduce l, normalize, subtract-projection, store ----
    const float xs = xsa[0];
    const int b = bh >> 4, h = bh & (NH - 1);
    const __bf16* Vb = V + (size_t)bh * SEQ * HD;
    #pragma unroll
    for (int mi = 0; mi < 2; mi++) {
        l_i[mi] += __shfl_xor(l_i[mi], 16);
        l_i[mi] += __shfl_xor(l_i[mi], 32);
        const int q = q0 + w * 32 + mi * 16 + l15;   // sequence position
        const float inv = 1.0f / l_i[mi];
        float vv[4][4], on[4][4];
        float dp = 0.0f, nn = 0.0f;
        #pragma unroll
        for (int db = 0; db < 4; db++) {
            __bf16 vb4[4];
            *(uint2*)vb4 = *(const uint2*)&Vb[(size_t)q * HD + db * 16 + quad * 4];
            #pragma unroll
            for (int r = 0; r < 4; r++) {
                const float vf = (float)vb4[r];
                const float of = o[mi][db][r] * inv;
                vv[db][r] = vf;
                on[db][r] = of;
                dp += of * vf;
                nn += vf * vf;
            }
        }
        dp += __shfl_xor(dp, 16); dp += __shfl_xor(dp, 32);
        nn += __shfl_xor(nn, 16); nn += __shfl_xor(nn, 32);
        const float coef = xs * dp / (nn + 1e-8f);
        #pragma unroll
        for (int db = 0; db < 4; db++) {
            __bf16 ob[4];
            #pragma unroll
            for (int r = 0; r < 4; r++)
                ob[r] = (__bf16)(on[db][r] - coef * vv[db][r]);
            *(uint2*)&X2[((size_t)b * SEQ + q) * DM + h * HD + db * 16 + quad * 4] =
                *(uint2*)ob;
        }
    }
}

// ======================================================================
extern "C" void kernel_launch(void* const* d_in, const int* in_sizes, int n_in,
                              void* d_out, int out_size, void* d_ws, size_t ws_size,
                              hipStream_t stream)
{
    (void)in_sizes; (void)n_in; (void)out_size; (void)ws_size;
    const float* x   = (const float*)d_in[0];
    const float* Wq  = (const float*)d_in[1];
    const float* Wk  = (const float*)d_in[2];
    const float* Wv  = (const float*)d_in[3];
    const float* Wo  = (const float*)d_in[4];
    const float* xsa = (const float*)d_in[5];
    float* out = (float*)d_out;

    // workspace layout (bf16 elements): 48 MB total.
    // X2 aliases xb: xb is only read by the QKV GEMM, which completes
    // (stream-ordered) before attn writes X2.
    __bf16* xb  = (__bf16*)d_ws;        // 4 M (x, bf16)  [aliased by X2]
    __bf16* Wb  = xb  + NEL;            // 4 x 1 M (Wq,Wk,Wv,Wo)
    __bf16* Qb  = Wb  + 4 * WEL;        // 4 M  (B,H,S,HD), pre-scaled
    __bf16* Kb  = Qb  + NEL;            // 4 M
    __bf16* Vb  = Kb  + NEL;            // 4 M
    __bf16* Vtb = Vb  + NEL;            // 4 M  (B,H,HD,S)
    __bf16* X2  = xb;                   // alias: (B,S,DM)

    // all fp32->bf16 conversions in one launch
    cvt_all<<<dim3(8192), 256, 0, stream>>>(x, Wq, Wk, Wv, Wo, xb, Wb);

    // Q/K/V projections (V transposed to Vt via LDS; Q pre-scaled)
    // 1D XCD-pinned grid: 8 xcd * 8 x * 12 (z,yq) = 768 blocks
    gemm_nt_mfma<128, 3><<<dim3(768), 256, 0, stream>>>(
        xb, Wb, Qb, Vtb, 1);

    // attention + fused subtract-projection -> X2 (1D XCD-pinned grid,
    // 128q / 4-wave blocks, KVBLK=128)
    attn_mfma<<<dim3((SEQ / 128) * BATCH * NH), 256, 0, stream>>>(
        Qb, Kb, Vtb, Vb, xsa, X2);

    // output projection, fp32 out; 1D XCD-pinned grid: 8*16*4 = 512 blocks
    gemm_nt_mfma<64, 1><<<dim3(512), 256, 0, stream>>>(
        X2, Wb + 3 * WEL, out, nullptr, 0);
}